// Round 5
// baseline (43.855 us; speedup 1.0000x reference)
//
#include <hip/hip_runtime.h>

#define IN_F    4096
#define OUT_F   11008
#define NGROUP  512        // IN_F / 8
#define CHUNK   16         // groups per thread per block
#define NCHUNK  (NGROUP / CHUNK)   // 32
#define OTILES  (OUT_F / 256)      // 43
#define BATCH   4
#define CBSIZE  65536

typedef int          iv4 __attribute__((ext_vector_type(4)));
typedef unsigned int uv4 __attribute__((ext_vector_type(4)));
typedef float        fv4 __attribute__((ext_vector_type(4)));

__device__ __forceinline__ unsigned bf16rne(float f) {
    unsigned u = __float_as_uint(f);
    return (u + 0x7fffu + ((u >> 16) & 1u)) >> 16;
}
__device__ __forceinline__ float blo(unsigned u) { return __uint_as_float(u << 16); }
__device__ __forceinline__ float bhi(unsigned u) { return __uint_as_float(u & 0xffff0000u); }

// Pack fp32 codebook [65536][8] -> bf16x2 [65536][4] u32 (16 B/entry) in d_ws.
// One code gather then needs only ONE dwordx4 instead of two.
__global__ __launch_bounds__(256) void pack_cb_kernel(
    const float* __restrict__ cb, unsigned* __restrict__ cbh)
{
    const int e = blockIdx.x * 256 + threadIdx.x;   // 256 blocks * 256 = 65536
    const fv4* src = (const fv4*)(cb + (size_t)e * 8);
    const fv4 a = src[0];
    const fv4 b = src[1];
    uv4 p;
    p.x = bf16rne(a.x) | (bf16rne(a.y) << 16);
    p.y = bf16rne(a.z) | (bf16rne(a.w) << 16);
    p.z = bf16rne(b.x) | (bf16rne(b.y) << 16);
    p.w = bf16rne(b.z) | (bf16rne(b.w) << 16);
    *((uv4*)(cbh + (size_t)e * 4)) = p;
}

// out[b][o] = bias[o]
__global__ __launch_bounds__(256) void init_out_kernel(
    const float* __restrict__ bias, float* __restrict__ out)
{
    const int o = blockIdx.x * 256 + threadIdx.x;
    out[(size_t)blockIdx.y * OUT_F + o] = bias[o];
}

// Each thread: one output o, CHUNK groups. One dwordx4 gather per code from
// the packed bf16 codebook (halves TA lane-requests vs fp32), all CHUNK
// gathers issued before any consume (sched_barrier-pinned) for MLP.
__global__ __launch_bounds__(256) void aqlm_kernel(
    const float*    __restrict__ x,       // [4][4096] fp32
    const unsigned* __restrict__ cbh,     // [65536][4] packed bf16x2
    const int*      __restrict__ codes,   // [11008][512]
    const float*    __restrict__ scales,  // [11008]
    float*          __restrict__ out)     // [4][11008]
{
    const int o  = blockIdx.x * 256 + threadIdx.x;
    const int g0 = blockIdx.y * CHUNK;

    // This lane's 16 codes: one fully-used 64-B cache line.
    int code[CHUNK];
    const iv4* cp = (const iv4*)(codes + (size_t)o * NGROUP + g0);
#pragma unroll
    for (int j = 0; j < CHUNK / 4; ++j) {
        const iv4 c = cp[j];
        code[4 * j + 0] = c.x;
        code[4 * j + 1] = c.y;
        code[4 * j + 2] = c.z;
        code[4 * j + 3] = c.w;
    }

    // Phase 1: issue all 16 dwordx4 gathers into registers.
    uv4 wq[CHUNK];
#pragma unroll
    for (int j = 0; j < CHUNK; ++j) {
        wq[j] = *((const uv4*)(cbh + (size_t)(unsigned)code[j] * 4u));
    }

    // Pin: no unpack/FMA hoisted above, no load sunk below.
    __builtin_amdgcn_sched_barrier(0);

    // Phase 2: unpack once per code, FMA over 4 batches.
    float acc[BATCH];
#pragma unroll
    for (int b = 0; b < BATCH; ++b) acc[b] = 0.f;

#pragma unroll
    for (int j = 0; j < CHUNK; ++j) {
        const float w0 = blo(wq[j].x), w1 = bhi(wq[j].x);
        const float w2 = blo(wq[j].y), w3 = bhi(wq[j].y);
        const float w4 = blo(wq[j].z), w5 = bhi(wq[j].z);
        const float w6 = blo(wq[j].w), w7 = bhi(wq[j].w);
        const float* xg = x + (size_t)(g0 + j) * 8;   // wave-uniform -> s_load
#pragma unroll
        for (int b = 0; b < BATCH; ++b) {
            const float* xb = xg + b * IN_F;
            acc[b] += xb[0] * w0 + xb[1] * w1 + xb[2] * w2 + xb[3] * w3
                    + xb[4] * w4 + xb[5] * w5 + xb[6] * w6 + xb[7] * w7;
        }
    }

    const float s = scales[o];
    atomicAdd(out + 0 * (size_t)OUT_F + o, s * acc[0]);
    atomicAdd(out + 1 * (size_t)OUT_F + o, s * acc[1]);
    atomicAdd(out + 2 * (size_t)OUT_F + o, s * acc[2]);
    atomicAdd(out + 3 * (size_t)OUT_F + o, s * acc[3]);
}

extern "C" void kernel_launch(void* const* d_in, const int* in_sizes, int n_in,
                              void* d_out, int out_size, void* d_ws, size_t ws_size,
                              hipStream_t stream) {
    const float* x      = (const float*)d_in[0];   // (4, 4096)
    const float* cb     = (const float*)d_in[1];   // (1, 65536, 1, 8)
    const int*   codes  = (const int*)d_in[2];     // (11008, 512, 1)
    const float* scales = (const float*)d_in[3];   // (11008, 1, 1, 1)
    const float* bias   = (const float*)d_in[4];   // (11008,)
    float* out = (float*)d_out;                    // (4, 11008)
    unsigned* cbh = (unsigned*)d_ws;               // 65536*16 B = 1 MB

    hipLaunchKernelGGL(pack_cb_kernel, dim3(CBSIZE / 256), dim3(256), 0, stream,
                       cb, cbh);
    hipLaunchKernelGGL(init_out_kernel, dim3(OTILES, BATCH), dim3(256), 0, stream,
                       bias, out);
    hipLaunchKernelGGL(aqlm_kernel, dim3(OTILES, NCHUNK), dim3(256), 0, stream,
                       x, cbh, codes, scales, out);
}